// Round 6
// baseline (5006.762 us; speedup 1.0000x reference)
//
#include <hip/hip_runtime.h>

#define SEQ   1024
#define HID   512
#define OUTD  10
#define RPB   16              // batch rows per row-group
#define NRG   32              // row-groups
#define NCG   2               // column-group blocks per row-group
#define CPB   (HID/NCG)       // 256 cols per block
#define NWV   8               // waves per block (512 threads)
#define CPWV  (CPB/NWV)       // 32 cols per wave
#define NT    (CPWV/16)       // 2 MFMA col-tiles per wave
#define NKT   (HID/32)        // 16 k-tiles of 32
#define OKT   (NKT/NCG)       // 8 own k-tiles
#define PCP   (CPB/2)         // 128 colpairs per panel row
#define PANEL (RPB*PCP)       // 2048 u64 words per panel

typedef float f32x4  __attribute__((ext_vector_type(4)));
typedef short bf16x8 __attribute__((ext_vector_type(8)));
typedef int   i32x4  __attribute__((ext_vector_type(4)));
typedef unsigned long long u64;

__device__ __forceinline__ unsigned short f2bf(float f) {
    unsigned u = __builtin_bit_cast(unsigned, f);
    u += 0x7fffu + ((u >> 16) & 1u);           // RTN
    return (unsigned short)(u >> 16);
}
__device__ __forceinline__ float bf2f(unsigned short s) {
    return __builtin_bit_cast(float, ((unsigned)s) << 16);
}

// hX: u64[2][NCG][NRG][PANEL]; word = 2 bf16 payload | step-tag<<32.
// Tag makes each word self-validating -> no flags, no fences (round 3 showed
// agent acquire/release = full L2 wb/inv per step). 0xAA poison never matches.
// NEAR path (sibling verified same XCD): volatile ld/st -> shared L2 (~200cyc).
// FAR path: relaxed agent atomics -> MALL (~700cyc), round-5 behavior.
__device__ __forceinline__ size_t panel_base(int buf, int cg, int rg) {
    return (((size_t)buf * NCG + cg) * NRG + rg) * PANEL;
}

__global__ __launch_bounds__(512, 2) void rnn_kernel(
    const float* __restrict__ x,     // [512][1024]
    const float* __restrict__ W_hx,  // [512][1]
    const float* __restrict__ b_hx,  // [512]
    const float* __restrict__ W_hh,  // [512][512]
    const float* __restrict__ b_hh,  // [512]
    const float* __restrict__ W_oh,  // [10][512]
    const float* __restrict__ b_oh,  // [10]
    float* __restrict__ out,         // [512][10]
    u64* __restrict__ hX,            // 2 MiB exchange buffer (ws)
    unsigned* __restrict__ xtab)     // 64-entry XCD handshake table (ws)
{
    __shared__ unsigned short hL[RPB * HID];   // 16 KB, XOR-swizzled h_t
    __shared__ float obuf[RPB][OUTD];
    __shared__ int sameLDS;
    char* const hLb = (char*)hL;

    const int tid  = threadIdx.x;
    const int lane = tid & 63;
    const int wv   = tid >> 6;        // 0..7
    const int bid  = blockIdx.x;
    const int rg   = bid & (NRG - 1);
    const int cg   = bid >> 5;        // 0..1
    const int row0 = rg * RPB;
    const int crow = lane & 15;       // A-row / B-col / D-col
    const int kb   = lane >> 4;
    const int dr0  = kb * 4;
    const int amask = (crow & 7) << 4;

    // ---- one-time XCD handshake: decide near (same-L2) vs far (MALL) ----
    if (tid == 0) {
        unsigned xcc;
        asm volatile("s_getreg_b32 %0, hwreg(HW_REG_XCC_ID)" : "=s"(xcc));
        xcc &= 0xFu;
        __hip_atomic_store(&xtab[bid], 0x5A5A0000u | xcc, __ATOMIC_RELAXED,
                           __HIP_MEMORY_SCOPE_AGENT);
        const int sib = (cg ^ 1) * NRG + rg;
        unsigned v;
        do {
            v = __hip_atomic_load(&xtab[sib], __ATOMIC_RELAXED,
                                  __HIP_MEMORY_SCOPE_AGENT);
        } while ((v & 0xFFFF0000u) != 0x5A5A0000u);
        sameLDS = ((v & 0xFu) == xcc) ? 1 : 0;
    }

    // slot->k-tile map: slots 0..7 own (A locally produced), 8..15 remote.
    int ktmap[NKT];
#pragma unroll
    for (int j = 0; j < OKT; ++j) {
        ktmap[j]       = cg * OKT + j;
        ktmap[OKT + j] = (cg ^ 1) * OKT + j;
    }

    // ---- W-slice -> registers (fp32 -> bf16, one-time; 128 VGPR) ----
    bf16x8 wfr[NT][NKT];
    float  whx[NT], bc[NT];
#pragma unroll
    for (int nt = 0; nt < NT; ++nt) {
        const int col = cg * CPB + wv * CPWV + nt * 16 + crow;
        whx[nt] = W_hx[col];
        bc[nt]  = b_hx[col] + b_hh[col];
#pragma unroll
        for (int j = 0; j < NKT; ++j) {
            const float* p = W_hh + (size_t)col * HID + ktmap[j] * 32 + kb * 8;
            bf16x8 v;
#pragma unroll
            for (int e = 0; e < 8; ++e) v[e] = (short)f2bf(p[e]);
            wfr[nt][j] = v;
        }
    }

    __syncthreads();                    // sameLDS published
    const bool nearp = (sameLDS != 0);

    // poll+fill: wait for the sibling panel's 4 words owned by this thread,
    // then write them into the sibling 256-col region of hL (one i32x4).
    const int prow = tid >> 5;             // 0..15
    const int pcp0 = (tid & 31) * 4;       // colpair base
    auto poll_fill = [&](int buf, unsigned want) {
        const u64* rp = hX + panel_base(buf, cg ^ 1, rg) + tid * 4;
        i32x4 w;
        if (nearp) {
            // 2 volatile 16B loads (sc0: L1-bypass, hits shared XCD L2)
            volatile const i32x4* vp = (volatile const i32x4*)rp;
            for (;;) {
                i32x4 a = vp[0];
                i32x4 b = vp[1];
                if ((unsigned)a[1] == want && (unsigned)a[3] == want &&
                    (unsigned)b[1] == want && (unsigned)b[3] == want) {
                    w[0] = a[0]; w[1] = a[2]; w[2] = b[0]; w[3] = b[2];
                    break;
                }
                __builtin_amdgcn_s_sleep(1);
            }
        } else {
            // far path: gated scalar polling via MALL (round-5 behavior)
            u64 vals[4];
            for (;;) {
                u64 v = __hip_atomic_load(rp, __ATOMIC_RELAXED,
                                          __HIP_MEMORY_SCOPE_AGENT);
                if ((unsigned)(v >> 32) == want) { vals[0] = v; break; }
                __builtin_amdgcn_s_sleep(1);
            }
            unsigned need = 0xEu;
            while (need) {
#pragma unroll
                for (int j = 1; j < 4; ++j) {
                    const unsigned b = 1u << j;
                    if (need & b) {
                        u64 v = __hip_atomic_load(rp + j, __ATOMIC_RELAXED,
                                                  __HIP_MEMORY_SCOPE_AGENT);
                        if ((unsigned)(v >> 32) == want) { vals[j] = v; need &= ~b; }
                    }
                }
                if (need) __builtin_amdgcn_s_sleep(1);
            }
#pragma unroll
            for (int j = 0; j < 4; ++j) w[j] = (int)(unsigned)vals[j];
        }
        int ad = (prow * 1024 + (cg ^ 1) * 512 + pcp0 * 4) ^ ((prow & 7) << 4);
        *(i32x4*)(hLb + ad) = w;
    };

    f32x4 acc[NT];

    for (int t = 0; t < SEQ; ++t) {
        float xv[4];
#pragma unroll
        for (int r = 0; r < 4; ++r)
            xv[r] = x[(size_t)(row0 + dr0 + r) * SEQ + t];

#pragma unroll
        for (int nt = 0; nt < NT; ++nt) acc[nt] = (f32x4){0.f, 0.f, 0.f, 0.f};

        if (t > 0) {
            // own-k GEMM (A = our own h-slice, written to hL last step)
#pragma unroll
            for (int j = 0; j < OKT; ++j) {
                int ad = (crow * 1024 + ktmap[j] * 64 + kb * 16) ^ amask;
                bf16x8 a = *(const bf16x8*)(hLb + ad);
                acc[0] = __builtin_amdgcn_mfma_f32_16x16x32_bf16(a, wfr[0][j], acc[0], 0, 0, 0);
                acc[1] = __builtin_amdgcn_mfma_f32_16x16x32_bf16(a, wfr[1][j], acc[1], 0, 0, 0);
            }
            // wait for the sibling slice, fill hL remote region
            poll_fill(t & 1, (unsigned)t);
            __syncthreads();   // B2: remote region complete; own-k reads done
            // remote-k GEMM
#pragma unroll
            for (int j = OKT; j < NKT; ++j) {
                int ad = (crow * 1024 + ktmap[j] * 64 + kb * 16) ^ amask;
                bf16x8 a = *(const bf16x8*)(hLb + ad);
                acc[0] = __builtin_amdgcn_mfma_f32_16x16x32_bf16(a, wfr[0][j], acc[0], 0, 0, 0);
                acc[1] = __builtin_amdgcn_mfma_f32_16x16x32_bf16(a, wfr[1][j], acc[1], 0, 0, 0);
            }
        }

        // ---- epilogue: tanh, publish tagged words first (drain early), then hL ----
        u64* const wp = hX + panel_base((t + 1) & 1, cg, rg);
        const u64 tag = ((u64)(unsigned)(t + 1)) << 32;
#pragma unroll
        for (int nt = 0; nt < NT; ++nt) {
#pragma unroll
            for (int r = 0; r < 4; ++r) {
                float pre = acc[nt][r] + xv[r] * whx[nt] + bc[nt];
                float e   = __expf(2.0f * pre);      // overflow -> inf -> h=1
                float h   = 1.0f - 2.0f / (e + 1.0f);
                unsigned hu = f2bf(h);
                unsigned pv = __shfl_xor(hu, 1);     // partner col (all lanes)
                if (!(crow & 1)) {
                    unsigned payload = hu | (pv << 16);
                    const int row = dr0 + r;
                    const int cpl = wv * 16 + nt * 8 + (crow >> 1);
                    u64* p = wp + row * PCP + cpl;
                    u64 word = (u64)payload | tag;
                    if (nearp) *(volatile u64*)p = word;     // lands in shared L2
                    else __hip_atomic_store(p, word, __ATOMIC_RELAXED,
                                            __HIP_MEMORY_SCOPE_AGENT);
                    int ad = (row * 1024 + (cg * CPB + wv * CPWV + nt * 16 + crow) * 2)
                             ^ ((row & 7) << 4);
                    *(unsigned*)(hLb + ad) = payload;
                }
            }
        }
        __syncthreads();   // Be: hL own region visible; remote reads retired
    }

    // ---- output projection + softmax (cg==0 blocks only) ----
    if (cg != 0) return;
    poll_fill(SEQ & 1, (unsigned)SEQ);   // final sibling slice
    __syncthreads();

    if (tid < RPB * OUTD) {
        const int bl = tid / OUTD, j = tid % OUTD;
        const float* wrow = W_oh + (size_t)j * HID;
        float s = b_oh[j];
        for (int k = 0; k < HID; ++k) {
            int ad = (bl * 1024 + k * 2) ^ ((bl & 7) << 4);
            s += bf2f(*(const unsigned short*)(hLb + ad)) * wrow[k];
        }
        obuf[bl][j] = s;
    }
    __syncthreads();
    if (tid < RPB) {
        float m = -1e30f;
#pragma unroll
        for (int j = 0; j < OUTD; ++j) m = fmaxf(m, obuf[tid][j]);
        float e[OUTD], ss = 0.f;
#pragma unroll
        for (int j = 0; j < OUTD; ++j) { e[j] = __expf(obuf[tid][j] - m); ss += e[j]; }
        float inv = 1.0f / ss;
#pragma unroll
        for (int j = 0; j < OUTD; ++j)
            out[(size_t)(row0 + tid) * OUTD + j] = e[j] * inv;
    }
}

extern "C" void kernel_launch(void* const* d_in, const int* in_sizes, int n_in,
                              void* d_out, int out_size, void* d_ws, size_t ws_size,
                              hipStream_t stream) {
    (void)in_sizes; (void)n_in; (void)out_size; (void)ws_size;
    const float* x    = (const float*)d_in[0];
    const float* W_hx = (const float*)d_in[1];
    const float* b_hx = (const float*)d_in[2];
    const float* W_hh = (const float*)d_in[3];
    const float* b_hh = (const float*)d_in[4];
    const float* W_oh = (const float*)d_in[5];
    const float* b_oh = (const float*)d_in[6];
    float* out = (float*)d_out;
    u64* hX = (u64*)d_ws;                      // 2 MiB tagged exchange
    unsigned* xtab = (unsigned*)((char*)d_ws + 2u * 1024 * 1024);  // 256 B
                                               // (ws >= 2MiB+512B proven in r3)

    rnn_kernel<<<dim3(NRG * NCG), dim3(512), 0, stream>>>(
        x, W_hx, b_hx, W_hh, b_hh, W_oh, b_oh, out, hX, xtab);
}

// Round 7
// 4209.930 us; speedup vs baseline: 1.1893x; 1.1893x over previous
//
#include <hip/hip_runtime.h>

#define SEQ   1024
#define HID   512
#define OUTD  10
#define RPB   16              // batch rows per block
#define NBLK  32              // 512 / RPB — one block per row-group, NO exchange
#define NWV   8               // waves per block (512 threads)
#define NKT   16              // k-tiles of 32

typedef float f32x4  __attribute__((ext_vector_type(4)));
typedef short bf16x8 __attribute__((ext_vector_type(8)));
typedef int   i32x4  __attribute__((ext_vector_type(4)));

__device__ __forceinline__ unsigned short f2bf(float f) {
    unsigned u = __builtin_bit_cast(unsigned, f);
    u += 0x7fffu + ((u >> 16) & 1u);           // RTN
    return (unsigned short)(u >> 16);
}
__device__ __forceinline__ float bf2f(unsigned short s) {
    return __builtin_bit_cast(float, ((unsigned)s) << 16);
}

// Pre-tiled bf16 W in ws: chunk c in [0,32768). T=c>>10 (col-tile), kt=(c>>6)&15,
// l=c&63. Chunk holds 8 bf16 = B-fragment of lane l for (tile T, k-tile kt):
// col = T*16 + (l&15), k = kt*32 + (l>>4)*8 + j. Per-wave per-kt load is then
// one contiguous 1KB block (lane-linear 16B) — perfect coalescing.
__global__ void w_prep(const float* __restrict__ W, unsigned short* __restrict__ Wt) {
    const int c  = blockIdx.x * 256 + threadIdx.x;   // 32768 chunks
    const int l  = c & 63, kt = (c >> 6) & 15, T = c >> 10;
    const int col = T * 16 + (l & 15);
    const int k0  = kt * 32 + (l >> 4) * 8;
    const float* s = W + (size_t)col * HID + k0;
    unsigned short v[8];
#pragma unroll
    for (int j = 0; j < 8; ++j) v[j] = f2bf(s[j]);
    i32x4 pk;
#pragma unroll
    for (int j = 0; j < 4; ++j)
        pk[j] = (int)((unsigned)v[2*j] | ((unsigned)v[2*j+1] << 16));
    *(i32x4*)(Wt + (size_t)c * 8) = pk;
}

// 3-tier W placement per wave w (4 col-tiles each):
//   T0=2w, T1=2w+1  -> VGPRs (128 regs)     [tiles 0..15  = cols 0..255]
//   T2=16+w         -> LDS (128 KB, 1-time) [tiles 16..23 = cols 256..383]
//   T3=24+w         -> streamed from L2     [tiles 24..31 = cols 384..511]
// h stays in LDS (16 KB, XOR-swizzled); 2 barriers/step; no global h traffic.
// MFMA 16x16x32 bf16: A lane l -> row=l&15, k=(l>>4)*8+j ; B -> col=l&15 same k;
// D -> col=l&15, row=(l>>4)*4+r  [verified rounds 2-6].
__global__ __launch_bounds__(512, 2) void rnn_kernel(
    const float* __restrict__ x,     // [512][1024]
    const float* __restrict__ W_hx,  // [512][1]
    const float* __restrict__ b_hx,  // [512]
    const float* __restrict__ b_hh,  // [512]
    const unsigned short* __restrict__ Wt,  // tiled bf16 W (ws)
    const float* __restrict__ W_oh,  // [10][512]
    const float* __restrict__ b_oh,  // [10]
    float* __restrict__ out)         // [512][10]
{
    __shared__ unsigned short Wlds[8 * NKT * 64 * 8];  // 128 KB: tiles 16..23
    __shared__ unsigned short hL[RPB * HID];           // 16 KB swizzled
    __shared__ float obuf[RPB][OUTD];
    char* const hLb = (char*)hL;

    const int tid  = threadIdx.x;
    const int lane = tid & 63;
    const int wv   = tid >> 6;        // 0..7
    const int row0 = blockIdx.x * RPB;
    const int crow = lane & 15;
    const int kb   = lane >> 4;
    const int dr0  = kb * 4;
    const int amask = (crow & 7) << 4;

    // ---- one-time: W reg tiles ----
    bf16x8 wfr0[NKT], wfr1[NKT];
    const int T0 = 2 * wv, T1 = 2 * wv + 1, T3 = 24 + wv;
#pragma unroll
    for (int kt = 0; kt < NKT; ++kt) {
        wfr0[kt] = *(const bf16x8*)(Wt + ((size_t)(T0 * NKT + kt) * 64 + lane) * 8);
        wfr1[kt] = *(const bf16x8*)(Wt + ((size_t)(T1 * NKT + kt) * 64 + lane) * 8);
    }
    // ---- one-time: LDS W tiles 16..23 (linear copy, 128 KB) ----
    for (int c = tid; c < 8192; c += 512)   // 16B chunks
        ((i32x4*)Wlds)[c] = *(const i32x4*)(Wt + 131072 + (size_t)c * 8);

    // per-tile column constants
    int   colv[4]; float whx[4], bc[4];
    const int Tarr[4] = {T0, T1, 16 + wv, T3};
#pragma unroll
    for (int nt = 0; nt < 4; ++nt) {
        colv[nt] = Tarr[nt] * 16 + crow;
        whx[nt]  = W_hx[colv[nt]];
        bc[nt]   = b_hx[colv[nt]] + b_hh[colv[nt]];
    }

    for (int i = tid; i < RPB * HID; i += 512) hL[i] = 0;   // h0 = 0
    __syncthreads();

    const int abase = crow * 1024 + kb * 16;
    const char* const wldsb = (const char*)Wlds;

    for (int t = 0; t < SEQ; ++t) {
        float xv[4];
#pragma unroll
        for (int r = 0; r < 4; ++r)
            xv[r] = x[(size_t)(row0 + dr0 + r) * SEQ + t];

        f32x4 acc[4];
#pragma unroll
        for (int nt = 0; nt < 4; ++nt) acc[nt] = (f32x4){0.f, 0.f, 0.f, 0.f};

        // rotating prefetch: a/bl depth-2 (LDS), bs depth-3 (L2)
        bf16x8 a[2], bl[2], bs[3];
        a[0]  = *(const bf16x8*)(hLb + ((abase + 0 * 64) ^ amask));
        a[1]  = *(const bf16x8*)(hLb + ((abase + 1 * 64) ^ amask));
        bl[0] = *(const bf16x8*)(wldsb + (size_t)((wv * NKT + 0) * 64 + lane) * 16);
        bl[1] = *(const bf16x8*)(wldsb + (size_t)((wv * NKT + 1) * 64 + lane) * 16);
        bs[0] = *(const bf16x8*)(Wt + ((size_t)(T3 * NKT + 0) * 64 + lane) * 8);
        bs[1] = *(const bf16x8*)(Wt + ((size_t)(T3 * NKT + 1) * 64 + lane) * 8);
        bs[2] = *(const bf16x8*)(Wt + ((size_t)(T3 * NKT + 2) * 64 + lane) * 8);

#pragma unroll
        for (int kt = 0; kt < NKT; ++kt) {
            const bf16x8 av = a[kt & 1];
            acc[0] = __builtin_amdgcn_mfma_f32_16x16x32_bf16(av, wfr0[kt], acc[0], 0, 0, 0);
            acc[1] = __builtin_amdgcn_mfma_f32_16x16x32_bf16(av, wfr1[kt], acc[1], 0, 0, 0);
            acc[2] = __builtin_amdgcn_mfma_f32_16x16x32_bf16(av, bl[kt & 1], acc[2], 0, 0, 0);
            acc[3] = __builtin_amdgcn_mfma_f32_16x16x32_bf16(av, bs[kt % 3], acc[3], 0, 0, 0);
            if (kt + 2 < NKT) {
                a[kt & 1]  = *(const bf16x8*)(hLb + ((abase + (kt + 2) * 64) ^ amask));
                bl[kt & 1] = *(const bf16x8*)(wldsb +
                               (size_t)((wv * NKT + kt + 2) * 64 + lane) * 16);
            }
            if (kt + 3 < NKT)
                bs[kt % 3] = *(const bf16x8*)(Wt +
                               ((size_t)(T3 * NKT + kt + 3) * 64 + lane) * 8);
        }

        __syncthreads();   // B1: all hL reads retired before rewrite

        // ---- epilogue: tanh, paired 4B writes into swizzled hL ----
#pragma unroll
        for (int nt = 0; nt < 4; ++nt) {
#pragma unroll
            for (int r = 0; r < 4; ++r) {
                float pre = acc[nt][r] + xv[r] * whx[nt] + bc[nt];
                float e   = __expf(2.0f * pre);      // overflow -> inf -> h=1
                float h   = 1.0f - 2.0f / (e + 1.0f);
                unsigned hu = f2bf(h);
                unsigned pv = __shfl_xor(hu, 1);     // partner column value
                if (!(crow & 1)) {
                    const int row = dr0 + r;
                    int ad = (row * 1024 + colv[nt] * 2) ^ ((row & 7) << 4);
                    *(unsigned*)(hLb + ad) = hu | (pv << 16);
                }
            }
        }
        __syncthreads();   // B2: h_{t+1} complete
    }

    // ---- output projection + softmax ----
    if (tid < RPB * OUTD) {
        const int bl2 = tid / OUTD, j = tid % OUTD;
        const float* wrow = W_oh + (size_t)j * HID;
        float s = b_oh[j];
        for (int k = 0; k < HID; ++k) {
            int ad = (bl2 * 1024 + k * 2) ^ ((bl2 & 7) << 4);
            s += bf2f(*(const unsigned short*)(hLb + ad)) * wrow[k];
        }
        obuf[bl2][j] = s;
    }
    __syncthreads();
    if (tid < RPB) {
        float m = -1e30f;
#pragma unroll
        for (int j = 0; j < OUTD; ++j) m = fmaxf(m, obuf[tid][j]);
        float e[OUTD], ss = 0.f;
#pragma unroll
        for (int j = 0; j < OUTD; ++j) { e[j] = __expf(obuf[tid][j] - m); ss += e[j]; }
        float inv = 1.0f / ss;
#pragma unroll
        for (int j = 0; j < OUTD; ++j)
            out[(size_t)(row0 + tid) * OUTD + j] = e[j] * inv;
    }
}

extern "C" void kernel_launch(void* const* d_in, const int* in_sizes, int n_in,
                              void* d_out, int out_size, void* d_ws, size_t ws_size,
                              hipStream_t stream) {
    (void)in_sizes; (void)n_in; (void)out_size; (void)ws_size;
    const float* x    = (const float*)d_in[0];
    const float* W_hx = (const float*)d_in[1];
    const float* b_hx = (const float*)d_in[2];
    const float* W_hh = (const float*)d_in[3];
    const float* b_hh = (const float*)d_in[4];
    const float* W_oh = (const float*)d_in[5];
    const float* b_oh = (const float*)d_in[6];
    float* out = (float*)d_out;
    unsigned short* Wt = (unsigned short*)d_ws;   // 512 KB tiled bf16 W

    w_prep<<<dim3(128), dim3(256), 0, stream>>>(W_hh, Wt);
    rnn_kernel<<<dim3(NBLK), dim3(512), 0, stream>>>(
        x, W_hx, b_hx, b_hh, Wt, W_oh, b_oh, out);
}

// Round 9
// 4183.936 us; speedup vs baseline: 1.1967x; 1.0062x over previous
//
#include <hip/hip_runtime.h>

#define SEQ   1024
#define HID   512
#define OUTD  10
#define RPB   16              // batch rows per block
#define NBLK  32              // 512 / RPB — one block per row-group, NO exchange
#define NWV   8               // waves per block (512 threads)
#define NKT   16              // k-tiles of 32

typedef float f32x4  __attribute__((ext_vector_type(4)));
typedef short bf16x8 __attribute__((ext_vector_type(8)));
typedef int   i32x4  __attribute__((ext_vector_type(4)));

__device__ __forceinline__ unsigned short f2bf(float f) {
    unsigned u = __builtin_bit_cast(unsigned, f);
    u += 0x7fffu + ((u >> 16) & 1u);           // RTN
    return (unsigned short)(u >> 16);
}
__device__ __forceinline__ float bf2f(unsigned short s) {
    return __builtin_bit_cast(float, ((unsigned)s) << 16);
}

// Pre-tiled bf16 W in ws: chunk c in [0,32768). T=c>>10 (col-tile), kt=(c>>6)&15,
// l=c&63. Chunk holds 8 bf16 = B-fragment of lane l for (tile T, k-tile kt):
// col = T*16 + (l&15), k = kt*32 + (l>>4)*8 + j. Per-wave per-kt load is then
// one contiguous 1KB block (lane-linear 16B) — perfect coalescing.
__global__ void w_prep(const float* __restrict__ W, unsigned short* __restrict__ Wt) {
    const int c  = blockIdx.x * 256 + threadIdx.x;   // 32768 chunks
    const int l  = c & 63, kt = (c >> 6) & 15, T = c >> 10;
    const int col = T * 16 + (l & 15);
    const int k0  = kt * 32 + (l >> 4) * 8;
    const float* s = W + (size_t)col * HID + k0;
    unsigned short v[8];
#pragma unroll
    for (int j = 0; j < 8; ++j) v[j] = f2bf(s[j]);
    i32x4 pk;
#pragma unroll
    for (int j = 0; j < 4; ++j)
        pk[j] = (int)((unsigned)v[2*j] | ((unsigned)v[2*j+1] << 16));
    *(i32x4*)(Wt + (size_t)c * 8) = pk;
}

// 3-tier W placement per wave w (4 col-tiles each):
//   T0=2w, T1=2w+1  -> VGPRs (128 regs, ASM-PINNED vs rematerialization)
//   T2=16+w         -> LDS (128 KB, 1-time) [tiles 16..23 = cols 256..383]
//   T3=24+w         -> streamed from L2     [tiles 24..31 = cols 384..511]
// h stays in LDS (16 KB, XOR-swizzled); 2 barriers/step; no global h traffic.
// MFMA 16x16x32 bf16: A lane l -> row=l&15, k=(l>>4)*8+j ; B -> col=l&15 same k;
// D -> col=l&15, row=(l>>4)*4+r  [verified rounds 2-7].
__global__ __launch_bounds__(512, 2) void rnn_kernel(
    const float* __restrict__ x,     // [512][1024]
    const float* __restrict__ W_hx,  // [512][1]
    const float* __restrict__ b_hx,  // [512]
    const float* __restrict__ b_hh,  // [512]
    const unsigned short* __restrict__ Wt,  // tiled bf16 W (ws)
    const float* __restrict__ W_oh,  // [10][512]
    const float* __restrict__ b_oh,  // [10]
    float* __restrict__ out)         // [512][10]
{
    __shared__ unsigned short Wlds[8 * NKT * 64 * 8];  // 128 KB: tiles 16..23
    __shared__ unsigned short hL[RPB * HID];           // 16 KB swizzled
    __shared__ float obuf[RPB][OUTD];
    char* const hLb = (char*)hL;

    const int tid  = threadIdx.x;
    const int lane = tid & 63;
    const int wv   = tid >> 6;        // 0..7
    const int row0 = blockIdx.x * RPB;
    const int crow = lane & 15;
    const int kb   = lane >> 4;
    const int dr0  = kb * 4;
    const int amask = (crow & 7) << 4;

    // ---- one-time: W reg tiles ----
    bf16x8 wfr0[NKT], wfr1[NKT];
    const int T0 = 2 * wv, T1 = 2 * wv + 1, T3 = 24 + wv;
#pragma unroll
    for (int kt = 0; kt < NKT; ++kt) {
        wfr0[kt] = *(const bf16x8*)(Wt + ((size_t)(T0 * NKT + kt) * 64 + lane) * 8);
        wfr1[kt] = *(const bf16x8*)(Wt + ((size_t)(T1 * NKT + kt) * 64 + lane) * 8);
    }
    // PIN: make each fragment asm-defined so the compiler cannot rematerialize
    // the load inside the t-loop (round 7: VGPR_Count=128 proved it reloaded
    // 256 KB/step from L2). Empty asm, value unchanged, origin now opaque.
#pragma unroll
    for (int kt = 0; kt < NKT; ++kt) {
        asm volatile("" : "+v"(wfr0[kt]));
        asm volatile("" : "+v"(wfr1[kt]));
    }

    // ---- one-time: LDS W tiles 16..23 (linear copy, 128 KB) ----
    for (int c = tid; c < 8192; c += 512)   // 16B chunks
        ((i32x4*)Wlds)[c] = *(const i32x4*)(Wt + 131072 + (size_t)c * 8);

    // per-tile column constants
    int   colv[4]; float whx[4], bc[4];
    const int Tarr[4] = {T0, T1, 16 + wv, T3};
#pragma unroll
    for (int nt = 0; nt < 4; ++nt) {
        colv[nt] = Tarr[nt] * 16 + crow;
        whx[nt]  = W_hx[colv[nt]];
        bc[nt]   = b_hx[colv[nt]] + b_hh[colv[nt]];
    }

    for (int i = tid; i < RPB * HID; i += 512) hL[i] = 0;   // h0 = 0
    __syncthreads();

    const int abase = crow * 1024 + kb * 16;
    const char* const wldsb = (const char*)Wlds;

    for (int t = 0; t < SEQ; ++t) {
        float xv[4];
#pragma unroll
        for (int r = 0; r < 4; ++r)
            xv[r] = x[(size_t)(row0 + dr0 + r) * SEQ + t];

        f32x4 acc[4];
#pragma unroll
        for (int nt = 0; nt < 4; ++nt) acc[nt] = (f32x4){0.f, 0.f, 0.f, 0.f};

        // rotating prefetch: a/bl depth-2 (LDS), bs depth-3 (L2)
        bf16x8 a[2], bl[2], bs[3];
        a[0]  = *(const bf16x8*)(hLb + ((abase + 0 * 64) ^ amask));
        a[1]  = *(const bf16x8*)(hLb + ((abase + 1 * 64) ^ amask));
        bl[0] = *(const bf16x8*)(wldsb + (size_t)((wv * NKT + 0) * 64 + lane) * 16);
        bl[1] = *(const bf16x8*)(wldsb + (size_t)((wv * NKT + 1) * 64 + lane) * 16);
        bs[0] = *(const bf16x8*)(Wt + ((size_t)(T3 * NKT + 0) * 64 + lane) * 8);
        bs[1] = *(const bf16x8*)(Wt + ((size_t)(T3 * NKT + 1) * 64 + lane) * 8);
        bs[2] = *(const bf16x8*)(Wt + ((size_t)(T3 * NKT + 2) * 64 + lane) * 8);

#pragma unroll
        for (int kt = 0; kt < NKT; ++kt) {
            const bf16x8 av = a[kt & 1];
            acc[0] = __builtin_amdgcn_mfma_f32_16x16x32_bf16(av, wfr0[kt], acc[0], 0, 0, 0);
            acc[1] = __builtin_amdgcn_mfma_f32_16x16x32_bf16(av, wfr1[kt], acc[1], 0, 0, 0);
            acc[2] = __builtin_amdgcn_mfma_f32_16x16x32_bf16(av, bl[kt & 1], acc[2], 0, 0, 0);
            acc[3] = __builtin_amdgcn_mfma_f32_16x16x32_bf16(av, bs[kt % 3], acc[3], 0, 0, 0);
            if (kt + 2 < NKT) {
                a[kt & 1]  = *(const bf16x8*)(hLb + ((abase + (kt + 2) * 64) ^ amask));
                bl[kt & 1] = *(const bf16x8*)(wldsb +
                               (size_t)((wv * NKT + kt + 2) * 64 + lane) * 16);
            }
            if (kt + 3 < NKT)
                bs[kt % 3] = *(const bf16x8*)(Wt +
                               ((size_t)(T3 * NKT + kt + 3) * 64 + lane) * 8);
        }

        __syncthreads();   // B1: all hL reads retired before rewrite

        // ---- epilogue: tanh, paired 4B writes into swizzled hL ----
#pragma unroll
        for (int nt = 0; nt < 4; ++nt) {
#pragma unroll
            for (int r = 0; r < 4; ++r) {
                float pre = acc[nt][r] + xv[r] * whx[nt] + bc[nt];
                float e   = __expf(2.0f * pre);      // overflow -> inf -> h=1
                float h   = 1.0f - 2.0f / (e + 1.0f);
                unsigned hu = f2bf(h);
                unsigned pv = __shfl_xor(hu, 1);     // partner column value
                if (!(crow & 1)) {
                    const int row = dr0 + r;
                    int ad = (row * 1024 + colv[nt] * 2) ^ ((row & 7) << 4);
                    *(unsigned*)(hLb + ad) = hu | (pv << 16);
                }
            }
        }
        __syncthreads();   // B2: h_{t+1} complete
    }

    // ---- output projection + softmax ----
    if (tid < RPB * OUTD) {
        const int bl2 = tid / OUTD, j = tid % OUTD;
        const float* wrow = W_oh + (size_t)j * HID;
        float s = b_oh[j];
        for (int k = 0; k < HID; ++k) {
            int ad = (bl2 * 1024 + k * 2) ^ ((bl2 & 7) << 4);
            s += bf2f(*(const unsigned short*)(hLb + ad)) * wrow[k];
        }
        obuf[bl2][j] = s;
    }
    __syncthreads();
    if (tid < RPB) {
        float m = -1e30f;
#pragma unroll
        for (int j = 0; j < OUTD; ++j) m = fmaxf(m, obuf[tid][j]);
        float e[OUTD], ss = 0.f;
#pragma unroll
        for (int j = 0; j < OUTD; ++j) { e[j] = __expf(obuf[tid][j] - m); ss += e[j]; }
        float inv = 1.0f / ss;
#pragma unroll
        for (int j = 0; j < OUTD; ++j)
            out[(size_t)(row0 + tid) * OUTD + j] = e[j] * inv;
    }
}

extern "C" void kernel_launch(void* const* d_in, const int* in_sizes, int n_in,
                              void* d_out, int out_size, void* d_ws, size_t ws_size,
                              hipStream_t stream) {
    (void)in_sizes; (void)n_in; (void)out_size; (void)ws_size;
    const float* x    = (const float*)d_in[0];
    const float* W_hx = (const float*)d_in[1];
    const float* b_hx = (const float*)d_in[2];
    const float* W_hh = (const float*)d_in[3];
    const float* b_hh = (const float*)d_in[4];
    const float* W_oh = (const float*)d_in[5];
    const float* b_oh = (const float*)d_in[6];
    float* out = (float*)d_out;
    unsigned short* Wt = (unsigned short*)d_ws;   // 512 KB tiled bf16 W

    w_prep<<<dim3(128), dim3(256), 0, stream>>>(W_hh, Wt);
    rnn_kernel<<<dim3(NBLK), dim3(512), 0, stream>>>(
        x, W_hx, b_hx, b_hh, Wt, W_oh, b_oh, out);
}

// Round 10
// 3950.120 us; speedup vs baseline: 1.2675x; 1.0592x over previous
//
#include <hip/hip_runtime.h>

#define SEQ   1024
#define HID   512
#define OUTD  10
#define RPB   16              // batch rows per block
#define NBLK  32              // 512 / RPB — one block per row-group, NO exchange
#define NWV   8               // waves per block (512 threads)
#define NKT   16              // k-tiles of 32

typedef float f32x4  __attribute__((ext_vector_type(4)));
typedef short bf16x8 __attribute__((ext_vector_type(8)));
typedef int   i32x4  __attribute__((ext_vector_type(4)));

__device__ __forceinline__ unsigned short f2bf(float f) {
    unsigned u = __builtin_bit_cast(unsigned, f);
    u += 0x7fffu + ((u >> 16) & 1u);           // RTN
    return (unsigned short)(u >> 16);
}
__device__ __forceinline__ float bf2f(unsigned short s) {
    return __builtin_bit_cast(float, ((unsigned)s) << 16);
}

// Pre-tiled bf16 W in ws: chunk c in [0,32768). T=c>>10 (col-tile), kt=(c>>6)&15,
// l=c&63. Chunk holds 8 bf16 = B-fragment of lane l for (tile T, k-tile kt):
// col = T*16 + (l&15), k = kt*32 + (l>>4)*8 + j. Per-wave per-kt load is then
// one contiguous 1KB block (lane-linear 16B) — perfect coalescing.
__global__ void w_prep(const float* __restrict__ W, unsigned short* __restrict__ Wt) {
    const int c  = blockIdx.x * 256 + threadIdx.x;   // 32768 chunks
    const int l  = c & 63, kt = (c >> 6) & 15, T = c >> 10;
    const int col = T * 16 + (l & 15);
    const int k0  = kt * 32 + (l >> 4) * 8;
    const float* s = W + (size_t)col * HID + k0;
    unsigned short v[8];
#pragma unroll
    for (int j = 0; j < 8; ++j) v[j] = f2bf(s[j]);
    i32x4 pk;
#pragma unroll
    for (int j = 0; j < 4; ++j)
        pk[j] = (int)((unsigned)v[2*j] | ((unsigned)v[2*j+1] << 16));
    *(i32x4*)(Wt + (size_t)c * 8) = pk;
}

// 3-tier W placement per wave w (4 col-tiles each):
//   T0=2w, T1=2w+1  -> AGPRs (128 regs, asm "=a" pinned — cannot be remat'd;
//                      gfx950 unified file: builtin MFMA reads AGPR directly)
//   T2=16+w         -> LDS (128 KB, 1-time) [tiles 16..23 = cols 256..383]
//   T3=24+w         -> streamed from L2     [tiles 24..31 = cols 384..511]
// LDS (148 KB) caps occupancy at 1 block/CU = 2 waves/SIMD; waves_per_eu(2,2)
// tells the allocator exactly that (256-reg budget) so it has no occupancy
// motive to reload W in-loop (rounds 7/9: VGPR_Count=128 proved remat).
// h stays in LDS (16 KB, XOR-swizzled); 2 barriers/step; no global h traffic.
// MFMA 16x16x32 bf16: A lane l -> row=l&15, k=(l>>4)*8+j ; B -> col=l&15 same k;
// D -> col=l&15, row=(l>>4)*4+r  [verified rounds 2-9].
__global__ __launch_bounds__(512)
__attribute__((amdgpu_waves_per_eu(2, 2)))
void rnn_kernel(
    const float* __restrict__ x,     // [512][1024]
    const float* __restrict__ W_hx,  // [512][1]
    const float* __restrict__ b_hx,  // [512]
    const float* __restrict__ b_hh,  // [512]
    const unsigned short* __restrict__ Wt,  // tiled bf16 W (ws)
    const float* __restrict__ W_oh,  // [10][512]
    const float* __restrict__ b_oh,  // [10]
    float* __restrict__ out)         // [512][10]
{
    __shared__ unsigned short Wlds[8 * NKT * 64 * 8];  // 128 KB: tiles 16..23
    __shared__ unsigned short hL[RPB * HID];           // 16 KB swizzled
    __shared__ float obuf[RPB][OUTD];
    char* const hLb = (char*)hL;

    const int tid  = threadIdx.x;
    const int lane = tid & 63;
    const int wv   = tid >> 6;        // 0..7
    const int row0 = blockIdx.x * RPB;
    const int crow = lane & 15;
    const int kb   = lane >> 4;
    const int dr0  = kb * 4;
    const int amask = (crow & 7) << 4;

    // ---- one-time: W reg tiles, pinned into AGPRs ----
    bf16x8 wfr0[NKT], wfr1[NKT];
    const int T0 = 2 * wv, T1 = 2 * wv + 1, T3 = 24 + wv;
#pragma unroll
    for (int kt = 0; kt < NKT; ++kt) {
        bf16x8 t0 = *(const bf16x8*)(Wt + ((size_t)(T0 * NKT + kt) * 64 + lane) * 8);
        bf16x8 t1 = *(const bf16x8*)(Wt + ((size_t)(T1 * NKT + kt) * 64 + lane) * 8);
        // Force into AGPR storage; asm-defined => rematerialization illegal.
        asm volatile("" : "=a"(wfr0[kt]) : "0"(t0));
        asm volatile("" : "=a"(wfr1[kt]) : "0"(t1));
    }

    // ---- one-time: LDS W tiles 16..23 (linear copy, 128 KB) ----
    for (int c = tid; c < 8192; c += 512)   // 16B chunks
        ((i32x4*)Wlds)[c] = *(const i32x4*)(Wt + 131072 + (size_t)c * 8);

    // per-tile column constants
    int   colv[4]; float whx[4], bc[4];
    const int Tarr[4] = {T0, T1, 16 + wv, T3};
#pragma unroll
    for (int nt = 0; nt < 4; ++nt) {
        colv[nt] = Tarr[nt] * 16 + crow;
        whx[nt]  = W_hx[colv[nt]];
        bc[nt]   = b_hx[colv[nt]] + b_hh[colv[nt]];
    }

    for (int i = tid; i < RPB * HID; i += 512) hL[i] = 0;   // h0 = 0
    __syncthreads();

    const int abase = crow * 1024 + kb * 16;
    const char* const wldsb = (const char*)Wlds;

    for (int t = 0; t < SEQ; ++t) {
        float xv[4];
#pragma unroll
        for (int r = 0; r < 4; ++r)
            xv[r] = x[(size_t)(row0 + dr0 + r) * SEQ + t];

        f32x4 acc[4];
#pragma unroll
        for (int nt = 0; nt < 4; ++nt) acc[nt] = (f32x4){0.f, 0.f, 0.f, 0.f};

        // rotating prefetch: a/bl depth-2 (LDS), bs depth-3 (L2)
        bf16x8 a[2], bl[2], bs[3];
        a[0]  = *(const bf16x8*)(hLb + ((abase + 0 * 64) ^ amask));
        a[1]  = *(const bf16x8*)(hLb + ((abase + 1 * 64) ^ amask));
        bl[0] = *(const bf16x8*)(wldsb + (size_t)((wv * NKT + 0) * 64 + lane) * 16);
        bl[1] = *(const bf16x8*)(wldsb + (size_t)((wv * NKT + 1) * 64 + lane) * 16);
        bs[0] = *(const bf16x8*)(Wt + ((size_t)(T3 * NKT + 0) * 64 + lane) * 8);
        bs[1] = *(const bf16x8*)(Wt + ((size_t)(T3 * NKT + 1) * 64 + lane) * 8);
        bs[2] = *(const bf16x8*)(Wt + ((size_t)(T3 * NKT + 2) * 64 + lane) * 8);

#pragma unroll
        for (int kt = 0; kt < NKT; ++kt) {
            const bf16x8 av = a[kt & 1];
            acc[0] = __builtin_amdgcn_mfma_f32_16x16x32_bf16(av, wfr0[kt], acc[0], 0, 0, 0);
            acc[1] = __builtin_amdgcn_mfma_f32_16x16x32_bf16(av, wfr1[kt], acc[1], 0, 0, 0);
            acc[2] = __builtin_amdgcn_mfma_f32_16x16x32_bf16(av, bl[kt & 1], acc[2], 0, 0, 0);
            acc[3] = __builtin_amdgcn_mfma_f32_16x16x32_bf16(av, bs[kt % 3], acc[3], 0, 0, 0);
            if (kt + 2 < NKT) {
                a[kt & 1]  = *(const bf16x8*)(hLb + ((abase + (kt + 2) * 64) ^ amask));
                bl[kt & 1] = *(const bf16x8*)(wldsb +
                               (size_t)((wv * NKT + kt + 2) * 64 + lane) * 16);
            }
            if (kt + 3 < NKT)
                bs[kt % 3] = *(const bf16x8*)(Wt +
                               ((size_t)(T3 * NKT + kt + 3) * 64 + lane) * 8);
        }

        __syncthreads();   // B1: all hL reads retired before rewrite

        // ---- epilogue: tanh, paired 4B writes into swizzled hL ----
#pragma unroll
        for (int nt = 0; nt < 4; ++nt) {
#pragma unroll
            for (int r = 0; r < 4; ++r) {
                float pre = acc[nt][r] + xv[r] * whx[nt] + bc[nt];
                float e   = __expf(2.0f * pre);      // overflow -> inf -> h=1
                float h   = 1.0f - 2.0f / (e + 1.0f);
                unsigned hu = f2bf(h);
                unsigned pv = __shfl_xor(hu, 1);     // partner column value
                if (!(crow & 1)) {
                    const int row = dr0 + r;
                    int ad = (row * 1024 + colv[nt] * 2) ^ ((row & 7) << 4);
                    *(unsigned*)(hLb + ad) = hu | (pv << 16);
                }
            }
        }
        __syncthreads();   // B2: h_{t+1} complete
    }

    // ---- output projection + softmax ----
    if (tid < RPB * OUTD) {
        const int bl2 = tid / OUTD, j = tid % OUTD;
        const float* wrow = W_oh + (size_t)j * HID;
        float s = b_oh[j];
        for (int k = 0; k < HID; ++k) {
            int ad = (bl2 * 1024 + k * 2) ^ ((bl2 & 7) << 4);
            s += bf2f(*(const unsigned short*)(hLb + ad)) * wrow[k];
        }
        obuf[bl2][j] = s;
    }
    __syncthreads();
    if (tid < RPB) {
        float m = -1e30f;
#pragma unroll
        for (int j = 0; j < OUTD; ++j) m = fmaxf(m, obuf[tid][j]);
        float e[OUTD], ss = 0.f;
#pragma unroll
        for (int j = 0; j < OUTD; ++j) { e[j] = __expf(obuf[tid][j] - m); ss += e[j]; }
        float inv = 1.0f / ss;
#pragma unroll
        for (int j = 0; j < OUTD; ++j)
            out[(size_t)(row0 + tid) * OUTD + j] = e[j] * inv;
    }
}

extern "C" void kernel_launch(void* const* d_in, const int* in_sizes, int n_in,
                              void* d_out, int out_size, void* d_ws, size_t ws_size,
                              hipStream_t stream) {
    (void)in_sizes; (void)n_in; (void)out_size; (void)ws_size;
    const float* x    = (const float*)d_in[0];
    const float* W_hx = (const float*)d_in[1];
    const float* b_hx = (const float*)d_in[2];
    const float* W_hh = (const float*)d_in[3];
    const float* b_hh = (const float*)d_in[4];
    const float* W_oh = (const float*)d_in[5];
    const float* b_oh = (const float*)d_in[6];
    float* out = (float*)d_out;
    unsigned short* Wt = (unsigned short*)d_ws;   // 512 KB tiled bf16 W

    w_prep<<<dim3(128), dim3(256), 0, stream>>>(W_hh, Wt);
    rnn_kernel<<<dim3(NBLK), dim3(512), 0, stream>>>(
        x, W_hx, b_hx, b_hh, Wt, W_oh, b_oh, out);
}